// Round 1
// baseline (281.904 us; speedup 1.0000x reference)
//
#include <hip/hip_runtime.h>
#include <stdint.h>
#include <stddef.h>

// ============================================================================
// MHA block on gfx950, bf16 MFMA pipeline.  B=2,S=2048,D=1024,H=16,hd=64.
// R6 changes vs R5 (qkv 68.7us @ MfmaUtil 13.2%, latency-bound: 2-barrier
// per K-step leaves global_load_lds latency exposed between barriers):
//  - All three MFMA kernels moved to the 2-phase double-buffered schedule
//    (T3 minimum recipe): stage tile t+1 into buf^1 BEFORE computing tile t
//    from buf, then a single __syncthreads() per step (its vmcnt/lgkmcnt
//    drain lands AFTER compute, so load latency hides under the MFMAs).
//  - qkv: LDS 32->64KB (2 blocks/CU), 15 pipelined iters + peeled tail.
//  - oproj: LDS 24->48KB, same structure.
//  - flash: Ks/Vs double-buffered (50KB w/ Ps, 3 blocks/CU); K/V tile kt+1
//    in flight across QK^T + softmax + PV of tile kt.
// Predictions: qkv 68.7->~42us (MfmaUtil ~22%), flash -15..25%, oproj -30%.
// MFMA layouts (verified m89/m91/m120):
//   A-frag: A[m=lane&15][k=(lane>>4)*8+j]  (16B/lane contiguous)
//   B-frag: B[k=(lane>>4)*8+j][n=lane&15] == row-major read of B^T tile
//   C/D:    col=lane&15, row=(lane>>4)*4+reg
// GEMM LDS fragment-major (BK=64): chunk(row,kc) = (row>>4)*128 + kc*16
//   + (row&15), kc = k>>3 in 0..7.  Wave stage base = (w+4*(q&1))*128
//   + 64*(q>>1), lane at +l -> wave-uniform base + lane*16B for
//   global_load_lds; frag reads are lane-contiguous 1KB blocks.
// ============================================================================

typedef __bf16 bf16x8 __attribute__((ext_vector_type(8)));
typedef float  f32x4  __attribute__((ext_vector_type(4)));

__device__ __forceinline__ unsigned short f2b(float f) {
  union { float f; uint32_t u; } v; v.f = f;
  uint32_t u = v.u;
  return (unsigned short)((u + 0x7FFFu + ((u >> 16) & 1u)) >> 16);  // RNE
}

__device__ __forceinline__ void async16(const void* g, void* l) {
  __builtin_amdgcn_global_load_lds(
      (const __attribute__((address_space(1))) void*)g,
      (__attribute__((address_space(3))) void*)l, 16, 0, 0);
}

// ---------------- cast x f32 -> bf16 ----------------
__global__ void cast_kernel(const float* __restrict__ in,
                            unsigned short* __restrict__ out, int n4) {
  int i = blockIdx.x * blockDim.x + threadIdx.x;
  if (i >= n4) return;
  float4 v = ((const float4*)in)[i];
  ushort4 o;
  o.x = f2b(v.x); o.y = f2b(v.y); o.z = f2b(v.z); o.w = f2b(v.w);
  ((ushort4*)out)[i] = o;
}

// ---------------- cast all 4 weight matrices in one launch ----------------
__global__ void cast_w_kernel(const float* __restrict__ wq, const float* __restrict__ wk,
                              const float* __restrict__ wv, const float* __restrict__ wo,
                              unsigned short* __restrict__ wqkv,
                              unsigned short* __restrict__ wobf) {
  int i = blockIdx.x * blockDim.x + threadIdx.x;   // 0 .. 4*2^18-1
  const int sel = i >> 18, k = i & ((1 << 18) - 1);
  const float* src = (sel == 0) ? wq : (sel == 1) ? wk : (sel == 2) ? wv : wo;
  float4 v = ((const float4*)src)[k];
  ushort4 o;
  o.x = f2b(v.x); o.y = f2b(v.y); o.z = f2b(v.z); o.w = f2b(v.w);
  if (sel < 3) ((ushort4*)wqkv)[(size_t)sel * 262144 + k] = o;
  else         ((ushort4*)wobf)[k] = o;
}

// ---------------- fused QKV projection GEMM (+bias, +RoPE on q/k) ----------
// C[4096,3072] = Xbf[4096,1024] @ Wqkv[3072,1024]^T, 128x128 tiles, BK=64,
// double-buffered 2-phase schedule.
// Output layouts:
//   q: [bh][2048][64] row-major (RoPE'd)
//   k: tiled frag-major: [bh][st=32][ chunk L = (d>>3)*64 + (s&63) ][8 of d]
//   v: V^T tiled frag-major: [bh][st=32][ chunk L = ((s&63)>>3)*64 + d ][8 of s]
__global__ __launch_bounds__(256) void qkv_gemm_kernel(
    const unsigned short* __restrict__ A,    // x_bf [4096][1024]
    const unsigned short* __restrict__ W,    // wqkv [3072][1024]
    const float* __restrict__ biasq, const float* __restrict__ biask,
    const float* __restrict__ biasv,
    const float* __restrict__ cp, const float* __restrict__ sp,  // [2048][32]
    unsigned short* __restrict__ qo,
    unsigned short* __restrict__ ko,
    unsigned short* __restrict__ vo)
{
  __shared__ unsigned short As[2][128 * 64];  // 2 x 16 KB
  __shared__ unsigned short Bs[2][128 * 64];  // 2 x 16 KB
  const int tid  = threadIdx.x;
  const int w    = tid >> 6, l = tid & 63;
  const int lm   = l & 15,  quad = l >> 4;
  const int nblk = blockIdx.x;               // 0..23
  const int m0   = blockIdx.y * 128;
  const int n0g  = nblk * 128;
  const int wm   = (w >> 1) * 64, wn = (w & 1) * 64;

  const f32x4 fzero = {0.f, 0.f, 0.f, 0.f};
  f32x4 acc[4][4];
#pragma unroll
  for (int i = 0; i < 4; ++i)
#pragma unroll
    for (int j = 0; j < 4; ++j) acc[i][j] = fzero;

  auto stage_tile = [&](int buf, int k0) {
#pragma unroll
    for (int q = 0; q < 4; ++q) {
      const int row = w * 16 + lm + (q & 1) * 64;
      const int kc  = quad + (q >> 1) * 4;
      const size_t ldsb = ((size_t)(w + 4 * (q & 1)) * 128 + 64 * (q >> 1)) * 8;
      async16(A + (size_t)(m0 + row) * 1024 + k0 + kc * 8, &As[buf][ldsb]);
      async16(W + (size_t)(n0g + row) * 1024 + k0 + kc * 8, &Bs[buf][ldsb]);
    }
  };
  auto compute_tile = [&](int buf) {
#pragma unroll
    for (int kk = 0; kk < 2; ++kk) {
      bf16x8 af[4], bfc[4];
#pragma unroll
      for (int i = 0; i < 4; ++i)
        af[i] = *(const bf16x8*)(&As[buf][(size_t)((((w >> 1) * 4 + i) * 128 + kk * 64 + l)) * 8]);
#pragma unroll
      for (int j = 0; j < 4; ++j)
        bfc[j] = *(const bf16x8*)(&Bs[buf][(size_t)((((w & 1) * 4 + j) * 128 + kk * 64 + l)) * 8]);
#pragma unroll
      for (int i = 0; i < 4; ++i)
#pragma unroll
        for (int j = 0; j < 4; ++j)
          acc[i][j] = __builtin_amdgcn_mfma_f32_16x16x32_bf16(af[i], bfc[j], acc[i][j], 0, 0, 0);
    }
  };

  // 2-phase pipeline: stage t+1, compute t, one barrier per step.
  stage_tile(0, 0);
  __syncthreads();                           // tile 0 resident
  int cur = 0;
  for (int t = 0; t < 15; ++t) {
    stage_tile(cur ^ 1, (t + 1) * 64);       // next tile in flight...
    compute_tile(cur);                       // ...under this tile's MFMAs
    __syncthreads();                         // drains vmcnt+lgkmcnt
    cur ^= 1;
  }
  compute_tile(cur);                         // tile 15 (no prefetch)

  const int which = nblk >> 3;               // 0=q 1=k 2=v
  const int n0    = (nblk & 7) * 128;
  const float* bias = (which == 0) ? biasq : (which == 1) ? biask : biasv;
#pragma unroll
  for (int i = 0; i < 4; ++i) {
#pragma unroll
    for (int j = 0; j < 4; ++j) {
      const int n = n0 + wn + j * 16 + lm;
      const float bval = bias[n];
      const int h = n >> 6, d = n & 63;
      float vals[4];
#pragma unroll
      for (int r = 0; r < 4; ++r) {
        const int m = m0 + wm + i * 16 + quad * 4 + r;
        const int srow = m & 2047;
        float val = acc[i][j][r] + bval;
        if (which != 2) {
          const float c  = cp[srow * 32 + (d >> 1)];
          const float sn = sp[srow * 32 + (d >> 1)];
          const float part = __shfl_xor(val, 1, 64);
          val = (d & 1) ? (part * sn + val * c) : (val * c - part * sn);
        }
        vals[r] = val;
      }
      const int mbase = m0 + wm + i * 16 + quad * 4;   // 4 consecutive s
      const int b = mbase >> 11, s0 = mbase & 2047;
      const int bh = (b << 4) + h;
      if (which == 0) {
#pragma unroll
        for (int r = 0; r < 4; ++r)
          qo[((size_t)bh * 2048 + s0 + r) * 64 + d] = f2b(vals[r]);
      } else if (which == 1) {
        // tiled: base = (bh*32 + s>>6)*4096 + ((d>>3)*64 + (s&63))*8 + (d&7)
#pragma unroll
        for (int r = 0; r < 4; ++r) {
          const int s = s0 + r;
          ko[((size_t)bh * 32 + (s >> 6)) * 4096 +
             (size_t)(((d >> 3) * 64 + (s & 63))) * 8 + (d & 7)] = f2b(vals[r]);
        }
      } else {
        // V^T tiled, 4 consecutive s -> one uint2 (8B) store
        uint32_t w0 = (uint32_t)f2b(vals[0]) | ((uint32_t)f2b(vals[1]) << 16);
        uint32_t w1 = (uint32_t)f2b(vals[2]) | ((uint32_t)f2b(vals[3]) << 16);
        uint2 pk; pk.x = w0; pk.y = w1;
        *(uint2*)(vo + ((size_t)bh * 32 + (s0 >> 6)) * 4096 +
                  (size_t)((((s0 & 63) >> 3) * 64 + d)) * 8 + (s0 & 7)) = pk;
      }
    }
  }
}

// ---------------- flash attention ----------------
// grid (bh=32, 16); block 512 thr = 8 waves; wave w owns q-rows w*16..w*16+15.
// S^T = K*Q^T formulation: t in-lane, m = lane&15.
// R6: K/V tiles double-buffered, next tile staged before QK^T of current.
__global__ __launch_bounds__(512, 4) void flash_kernel(
    const unsigned short* __restrict__ Q,    // [32][2048][64] row-major
    const unsigned short* __restrict__ K,    // tiled frag-major (see qkv)
    const unsigned short* __restrict__ VT,   // V^T tiled frag-major
    unsigned short* __restrict__ O)          // [2][2048][1024]
{
  constexpr int PSTRIDE = 72;                // Ps row stride (shorts)
  __shared__ unsigned short Ks[2][4096];     // 2 x 8 KB, chunk L = c*64 + t
  __shared__ unsigned short Vs[2][4096];     // 2 x 8 KB, chunk L = ct*64 + d
  __shared__ unsigned short Ps[128 * PSTRIDE];
  const int tid = threadIdx.x;
  const int w = tid >> 6, l = tid & 63, lm = l & 15, quad = l >> 4;
  const int bh = blockIdx.x, qb = 15 - blockIdx.y;   // heavy q-blocks first
  const int mrow_g = qb * 128 + w * 16 + lm;         // this lane's softmax row

  // Q fragment to registers: lane reads row (qb*128+w*16+lm), 8 d at quad*8
  const size_t qbase = ((size_t)bh * 2048 + (size_t)qb * 128) * 64;
  bf16x8 aq[2];
#pragma unroll
  for (int kc = 0; kc < 2; ++kc)
    aq[kc] = *(const bf16x8*)(Q + qbase + (size_t)(w * 16 + lm) * 64 + kc * 32 + quad * 8);

  const f32x4 fzero = {0.f, 0.f, 0.f, 0.f};
  f32x4 Oacc[4];
#pragma unroll
  for (int jo = 0; jo < 4; ++jo) Oacc[jo] = fzero;
  float m_i = -1e30f, l_i = 0.f;

  auto stageKV = [&](int buf, int kt) {
    const size_t tbase = ((size_t)bh * 32 + kt) * 4096;
    async16(K  + tbase + (size_t)tid * 8, &Ks[buf][(size_t)w * 512]);
    async16(VT + tbase + (size_t)tid * 8, &Vs[buf][(size_t)w * 512]);
  };

  const int nkv = 2 * qb + 2;
  stageKV(0, 0);
  __syncthreads();                           // tile 0 resident
  int cur = 0;
  for (int kt = 0; kt < nkv; ++kt) {
    if (kt + 1 < nkv) stageKV(cur ^ 1, kt + 1);   // next K/V in flight

    // S^T = K * Q^T : Sc[tb] holds t = tb*16+quad*4+r (rows), m = lm (col)
    f32x4 Sc[4];
#pragma unroll
    for (int tb = 0; tb < 4; ++tb) Sc[tb] = fzero;
#pragma unroll
    for (int kc = 0; kc < 2; ++kc) {
      bf16x8 ak[4];
#pragma unroll
      for (int tb = 0; tb < 4; ++tb)
        ak[tb] = *(const bf16x8*)(&Ks[cur][(size_t)(((kc * 4 + quad) * 64 + tb * 16 + lm)) * 8]);
#pragma unroll
      for (int tb = 0; tb < 4; ++tb)
        Sc[tb] = __builtin_amdgcn_mfma_f32_16x16x32_bf16(ak[tb], aq[kc], Sc[tb], 0, 0, 0);
    }

    // scale + causal mask.  Mask needed iff tile's max t (kt*64+63) exceeds
    // this wave's MIN row (qb*128 + w*16).
    const bool needmask = (kt * 64 + 63 > qb * 128 + w * 16);
    const int  mrel = mrow_g - kt * 64;      // mask t-index > mrel
    float mx = -1e30f;
#pragma unroll
    for (int tb = 0; tb < 4; ++tb) {
#pragma unroll
      for (int r = 0; r < 4; ++r) {
        float s = Sc[tb][r] * 0.125f;        // 1/sqrt(64)
        if (needmask && (tb * 16 + quad * 4 + r > mrel)) s = -1e30f;
        Sc[tb][r] = s;
        mx = fmaxf(mx, s);
      }
    }
    mx = fmaxf(mx, __shfl_xor(mx, 16, 64));
    mx = fmaxf(mx, __shfl_xor(mx, 32, 64));
    const float mnew  = fmaxf(m_i, mx);
    const float alpha = __expf(m_i - mnew);
    m_i = mnew;

    // exp, pack 4 consecutive t -> b64 write into Ps[m][t]
    float ps = 0.f;
#pragma unroll
    for (int tb = 0; tb < 4; ++tb) {
      float p0 = __expf(Sc[tb][0] - mnew), p1 = __expf(Sc[tb][1] - mnew);
      float p2 = __expf(Sc[tb][2] - mnew), p3 = __expf(Sc[tb][3] - mnew);
      ps += (p0 + p1) + (p2 + p3);
      uint2 pk;
      pk.x = (uint32_t)f2b(p0) | ((uint32_t)f2b(p1) << 16);
      pk.y = (uint32_t)f2b(p2) | ((uint32_t)f2b(p3) << 16);
      *(uint2*)(Ps + (size_t)(w * 16 + lm) * PSTRIDE + tb * 16 + quad * 4) = pk;
    }
    ps += __shfl_xor(ps, 16, 64);
    ps += __shfl_xor(ps, 32, 64);
    l_i = l_i * alpha + ps;

    // rescale Oacc: alpha lives per m=lm; O rows are quad*4+r -> shuffle
    float af4[4];
#pragma unroll
    for (int r = 0; r < 4; ++r) af4[r] = __shfl(alpha, quad * 4 + r, 64);
#pragma unroll
    for (int jo = 0; jo < 4; ++jo)
#pragma unroll
      for (int r = 0; r < 4; ++r) Oacc[jo][r] *= af4[r];

    // O += P V  (wave-private Ps rows; lgkmcnt orders write->read in-wave)
#pragma unroll
    for (int kc = 0; kc < 2; ++kc) {
      bf16x8 ap = *(const bf16x8*)(Ps + (size_t)(w * 16 + lm) * PSTRIDE + kc * 32 + quad * 8);
      bf16x8 bv[4];
#pragma unroll
      for (int jo = 0; jo < 4; ++jo)
        bv[jo] = *(const bf16x8*)(&Vs[cur][(size_t)(((kc * 4 + quad) * 64 + jo * 16 + lm)) * 8]);
#pragma unroll
      for (int jo = 0; jo < 4; ++jo)
        Oacc[jo] = __builtin_amdgcn_mfma_f32_16x16x32_bf16(ap, bv[jo], Oacc[jo], 0, 0, 0);
    }

    __syncthreads();                         // next tile resident; reads done
    cur ^= 1;
  }

  // epilogue: normalize, write o_bf (b, s, h*64+d)
  float lf[4];
#pragma unroll
  for (int r = 0; r < 4; ++r) lf[r] = 1.0f / __shfl(l_i, quad * 4 + r, 64);
  const int b = bh >> 4, h = bh & 15;
#pragma unroll
  for (int jo = 0; jo < 4; ++jo)
#pragma unroll
    for (int r = 0; r < 4; ++r) {
      const int s   = qb * 128 + w * 16 + quad * 4 + r;
      const int col = h * 64 + jo * 16 + lm;
      O[((size_t)b * 2048 + s) * 1024 + col] = f2b(Oacc[jo][r] * lf[r]);
    }
}

// ---------------- output projection GEMM ----------------
// out[4096,1024] = Obf[4096,1024] @ Wo[1024,1024]^T + bias (fp32 out).
// 64x128 tiles, BK=64, 512 blocks (2/CU), double-buffered 2-phase schedule.
__global__ __launch_bounds__(256) void oproj_gemm_kernel(
    const unsigned short* __restrict__ A,    // o_bf [4096][1024]
    const unsigned short* __restrict__ W,    // wo_bf [1024][1024]
    const float* __restrict__ bias,
    float* __restrict__ out)
{
  __shared__ unsigned short As[2][64 * 64];   // 2 x 8 KB
  __shared__ unsigned short Bs[2][128 * 64];  // 2 x 16 KB
  const int tid = threadIdx.x;
  const int w = tid >> 6, l = tid & 63;
  const int lm = l & 15, quad = l >> 4;
  const int m0 = blockIdx.y * 64;
  const int n0 = blockIdx.x * 128;

  const f32x4 fzero = {0.f, 0.f, 0.f, 0.f};
  f32x4 acc[4][2];
#pragma unroll
  for (int i = 0; i < 4; ++i)
#pragma unroll
    for (int j = 0; j < 2; ++j) acc[i][j] = fzero;

  auto stage_tile = [&](int buf, int k0) {
    // A: 64 rows x 8 kc = 512 chunks; 2 per thread
#pragma unroll
    for (int q = 0; q < 2; ++q) {
      const int row = w * 16 + lm;
      const int kc  = quad + 4 * q;
      async16(A + (size_t)(m0 + row) * 1024 + k0 + kc * 8,
              &As[buf][((size_t)w * 128 + 64 * q) * 8]);
    }
    // B: 128 rows x 8 kc = 1024 chunks; 4 per thread
#pragma unroll
    for (int q = 0; q < 4; ++q) {
      const int row = w * 16 + lm + (q & 1) * 64;
      const int kc  = quad + 4 * (q >> 1);
      async16(W + (size_t)(n0 + row) * 1024 + k0 + kc * 8,
              &Bs[buf][((size_t)(w + 4 * (q & 1)) * 128 + 64 * (q >> 1)) * 8]);
    }
  };
  auto compute_tile = [&](int buf) {
#pragma unroll
    for (int kk = 0; kk < 2; ++kk) {
      bf16x8 af[4], bfc[2];
#pragma unroll
      for (int i = 0; i < 4; ++i)
        af[i] = *(const bf16x8*)(&As[buf][(size_t)((i * 128 + kk * 64 + l)) * 8]);
#pragma unroll
      for (int j = 0; j < 2; ++j)
        bfc[j] = *(const bf16x8*)(&Bs[buf][(size_t)(((w * 2 + j) * 128 + kk * 64 + l)) * 8]);
#pragma unroll
      for (int i = 0; i < 4; ++i)
#pragma unroll
        for (int j = 0; j < 2; ++j)
          acc[i][j] = __builtin_amdgcn_mfma_f32_16x16x32_bf16(af[i], bfc[j], acc[i][j], 0, 0, 0);
    }
  };

  stage_tile(0, 0);
  __syncthreads();
  int cur = 0;
  for (int t = 0; t < 15; ++t) {
    stage_tile(cur ^ 1, (t + 1) * 64);
    compute_tile(cur);
    __syncthreads();
    cur ^= 1;
  }
  compute_tile(cur);

#pragma unroll
  for (int i = 0; i < 4; ++i) {
#pragma unroll
    for (int j = 0; j < 2; ++j) {
      const int n = n0 + w * 32 + j * 16 + lm;
      const float bval = bias[n];
#pragma unroll
      for (int r = 0; r < 4; ++r) {
        const int m = m0 + i * 16 + quad * 4 + r;
        out[(size_t)m * 1024 + n] = acc[i][j][r] + bval;
      }
    }
  }
}

// ---------------- host launch ----------------
extern "C" void kernel_launch(void* const* d_in, const int* in_sizes, int n_in,
                              void* d_out, int out_size, void* d_ws, size_t ws_size,
                              hipStream_t stream) {
  (void)in_sizes; (void)n_in; (void)out_size; (void)ws_size;
  const float* x  = (const float*)d_in[0];
  const float* cp = (const float*)d_in[1];
  const float* sp = (const float*)d_in[2];
  const float* wq = (const float*)d_in[3];
  const float* bq = (const float*)d_in[4];
  const float* wk = (const float*)d_in[5];
  const float* bk = (const float*)d_in[6];
  const float* wv = (const float*)d_in[7];
  const float* bv = (const float*)d_in[8];
  const float* wo = (const float*)d_in[9];
  const float* bo = (const float*)d_in[10];
  float* out = (float*)d_out;

  unsigned short* xbf  = (unsigned short*)d_ws;          // 4M shorts
  unsigned short* wqkv = xbf  + (size_t)4 * 1024 * 1024; // 3M
  unsigned short* wobf = wqkv + (size_t)3 * 1024 * 1024; // 1M
  unsigned short* qbf  = wobf + (size_t)1 * 1024 * 1024; // 4M (bh,s,d)
  unsigned short* kbf  = qbf  + (size_t)4 * 1024 * 1024; // 4M (tiled frag-major)
  unsigned short* vbf  = kbf  + (size_t)4 * 1024 * 1024; // 4M (V^T tiled)
  unsigned short* obf  = vbf  + (size_t)4 * 1024 * 1024; // 4M (b,s,h*64+d)

  hipLaunchKernelGGL(cast_kernel, dim3(4096), dim3(256), 0, stream, x, xbf, 1048576);
  hipLaunchKernelGGL(cast_w_kernel, dim3(4096), dim3(256), 0, stream,
                     wq, wk, wv, wo, wqkv, wobf);

  hipLaunchKernelGGL(qkv_gemm_kernel, dim3(24, 32), dim3(256), 0, stream,
                     xbf, wqkv, bq, bk, bv, cp, sp, qbf, kbf, vbf);
  hipLaunchKernelGGL(flash_kernel, dim3(32, 16), dim3(512), 0, stream,
                     qbf, kbf, vbf, obf);
  hipLaunchKernelGGL(oproj_gemm_kernel, dim3(8, 64), dim3(256), 0, stream,
                     obf, wobf, bo, out);
}

// Round 2
// 266.046 us; speedup vs baseline: 1.0596x; 1.0596x over previous
//
#include <hip/hip_runtime.h>
#include <stdint.h>
#include <stddef.h>

// ============================================================================
// MHA block on gfx950, bf16 MFMA pipeline.  B=2,S=2048,D=1024,H=16,hd=64.
// R7 changes vs R6 (qkv 107.8us @ MfmaUtil 9.2%: runtime-indexed double
// buffer defeated alias analysis -> compiler inserted vmcnt(0) before the
// ds_reads -> zero overlap, paid the 3->2 blocks/CU occupancy cost anyway):
//  - Pipeline loops explicitly unrolled x2 with STATIC ping/pong buffer
//    pointers (As[0]/As[1] literals).  Constant-offset GEPs are NoAlias, so
//    the vmcnt drain sinks into the post-compute __syncthreads() and the
//    staging latency hides under the MFMAs.  Same fix in qkv, flash, oproj.
//  - Everything else identical to R6.
// Predictions: qkv ~48us @ MfmaUtil ~22%; flash -10..20%; total ~185us.
// MFMA layouts (verified m89/m91/m120):
//   A-frag: A[m=lane&15][k=(lane>>4)*8+j]  (16B/lane contiguous)
//   B-frag: B[k=(lane>>4)*8+j][n=lane&15] == row-major read of B^T tile
//   C/D:    col=lane&15, row=(lane>>4)*4+reg
// GEMM LDS fragment-major (BK=64): chunk(row,kc) = (row>>4)*128 + kc*16
//   + (row&15), kc = k>>3 in 0..7.  Wave stage base = (w+4*(q&1))*128
//   + 64*(q>>1), lane at +l -> wave-uniform base + lane*16B for
//   global_load_lds; frag reads are lane-contiguous 1KB blocks.
// ============================================================================

typedef __bf16 bf16x8 __attribute__((ext_vector_type(8)));
typedef float  f32x4  __attribute__((ext_vector_type(4)));

__device__ __forceinline__ unsigned short f2b(float f) {
  union { float f; uint32_t u; } v; v.f = f;
  uint32_t u = v.u;
  return (unsigned short)((u + 0x7FFFu + ((u >> 16) & 1u)) >> 16);  // RNE
}

__device__ __forceinline__ void async16(const void* g, void* l) {
  __builtin_amdgcn_global_load_lds(
      (const __attribute__((address_space(1))) void*)g,
      (__attribute__((address_space(3))) void*)l, 16, 0, 0);
}

// ---------------- cast x f32 -> bf16 ----------------
__global__ void cast_kernel(const float* __restrict__ in,
                            unsigned short* __restrict__ out, int n4) {
  int i = blockIdx.x * blockDim.x + threadIdx.x;
  if (i >= n4) return;
  float4 v = ((const float4*)in)[i];
  ushort4 o;
  o.x = f2b(v.x); o.y = f2b(v.y); o.z = f2b(v.z); o.w = f2b(v.w);
  ((ushort4*)out)[i] = o;
}

// ---------------- cast all 4 weight matrices in one launch ----------------
__global__ void cast_w_kernel(const float* __restrict__ wq, const float* __restrict__ wk,
                              const float* __restrict__ wv, const float* __restrict__ wo,
                              unsigned short* __restrict__ wqkv,
                              unsigned short* __restrict__ wobf) {
  int i = blockIdx.x * blockDim.x + threadIdx.x;   // 0 .. 4*2^18-1
  const int sel = i >> 18, k = i & ((1 << 18) - 1);
  const float* src = (sel == 0) ? wq : (sel == 1) ? wk : (sel == 2) ? wv : wo;
  float4 v = ((const float4*)src)[k];
  ushort4 o;
  o.x = f2b(v.x); o.y = f2b(v.y); o.z = f2b(v.z); o.w = f2b(v.w);
  if (sel < 3) ((ushort4*)wqkv)[(size_t)sel * 262144 + k] = o;
  else         ((ushort4*)wobf)[k] = o;
}

// ---------------- fused QKV projection GEMM (+bias, +RoPE on q/k) ----------
// C[4096,3072] = Xbf[4096,1024] @ Wqkv[3072,1024]^T, 128x128 tiles, BK=64,
// double-buffered 2-phase schedule, static ping/pong.
// Output layouts:
//   q: [bh][2048][64] row-major (RoPE'd)
//   k: tiled frag-major: [bh][st=32][ chunk L = (d>>3)*64 + (s&63) ][8 of d]
//   v: V^T tiled frag-major: [bh][st=32][ chunk L = ((s&63)>>3)*64 + d ][8 of s]
__global__ __launch_bounds__(256) void qkv_gemm_kernel(
    const unsigned short* __restrict__ A,    // x_bf [4096][1024]
    const unsigned short* __restrict__ W,    // wqkv [3072][1024]
    const float* __restrict__ biasq, const float* __restrict__ biask,
    const float* __restrict__ biasv,
    const float* __restrict__ cp, const float* __restrict__ sp,  // [2048][32]
    unsigned short* __restrict__ qo,
    unsigned short* __restrict__ ko,
    unsigned short* __restrict__ vo)
{
  __shared__ unsigned short As[2][128 * 64];  // 2 x 16 KB
  __shared__ unsigned short Bs[2][128 * 64];  // 2 x 16 KB
  const int tid  = threadIdx.x;
  const int w    = tid >> 6, l = tid & 63;
  const int lm   = l & 15,  quad = l >> 4;
  const int nblk = blockIdx.x;               // 0..23
  const int m0   = blockIdx.y * 128;
  const int n0g  = nblk * 128;
  const int wm   = (w >> 1) * 64, wn = (w & 1) * 64;

  const f32x4 fzero = {0.f, 0.f, 0.f, 0.f};
  f32x4 acc[4][4];
#pragma unroll
  for (int i = 0; i < 4; ++i)
#pragma unroll
    for (int j = 0; j < 4; ++j) acc[i][j] = fzero;

  auto stage_tile = [&](unsigned short* Asb, unsigned short* Bsb, int k0) {
#pragma unroll
    for (int q = 0; q < 4; ++q) {
      const int row = w * 16 + lm + (q & 1) * 64;
      const int kc  = quad + (q >> 1) * 4;
      const size_t ldsb = ((size_t)(w + 4 * (q & 1)) * 128 + 64 * (q >> 1)) * 8;
      async16(A + (size_t)(m0 + row) * 1024 + k0 + kc * 8, Asb + ldsb);
      async16(W + (size_t)(n0g + row) * 1024 + k0 + kc * 8, Bsb + ldsb);
    }
  };
  auto compute_tile = [&](const unsigned short* Asb, const unsigned short* Bsb) {
#pragma unroll
    for (int kk = 0; kk < 2; ++kk) {
      bf16x8 af[4], bfc[4];
#pragma unroll
      for (int i = 0; i < 4; ++i)
        af[i] = *(const bf16x8*)(Asb + (size_t)((((w >> 1) * 4 + i) * 128 + kk * 64 + l)) * 8);
#pragma unroll
      for (int j = 0; j < 4; ++j)
        bfc[j] = *(const bf16x8*)(Bsb + (size_t)((((w & 1) * 4 + j) * 128 + kk * 64 + l)) * 8);
#pragma unroll
      for (int i = 0; i < 4; ++i)
#pragma unroll
        for (int j = 0; j < 4; ++j)
          acc[i][j] = __builtin_amdgcn_mfma_f32_16x16x32_bf16(af[i], bfc[j], acc[i][j], 0, 0, 0);
    }
  };

  // 2-phase pipeline, static ping/pong: stage t+1, compute t, one barrier.
  stage_tile(As[0], Bs[0], 0);
  __syncthreads();                           // tile 0 resident
#pragma unroll 1
  for (int t = 0; t < 14; t += 2) {
    stage_tile(As[1], Bs[1], (t + 1) * 64);  // next tile in flight...
    compute_tile(As[0], Bs[0]);              // ...under this tile's MFMAs
    __syncthreads();                         // drains vmcnt+lgkmcnt
    stage_tile(As[0], Bs[0], (t + 2) * 64);
    compute_tile(As[1], Bs[1]);
    __syncthreads();
  }
  stage_tile(As[1], Bs[1], 15 * 64);
  compute_tile(As[0], Bs[0]);                // tile 14
  __syncthreads();
  compute_tile(As[1], Bs[1]);                // tile 15 (no prefetch)

  const int which = nblk >> 3;               // 0=q 1=k 2=v
  const int n0    = (nblk & 7) * 128;
  const float* bias = (which == 0) ? biasq : (which == 1) ? biask : biasv;
#pragma unroll
  for (int i = 0; i < 4; ++i) {
#pragma unroll
    for (int j = 0; j < 4; ++j) {
      const int n = n0 + wn + j * 16 + lm;
      const float bval = bias[n];
      const int h = n >> 6, d = n & 63;
      float vals[4];
#pragma unroll
      for (int r = 0; r < 4; ++r) {
        const int m = m0 + wm + i * 16 + quad * 4 + r;
        const int srow = m & 2047;
        float val = acc[i][j][r] + bval;
        if (which != 2) {
          const float c  = cp[srow * 32 + (d >> 1)];
          const float sn = sp[srow * 32 + (d >> 1)];
          const float part = __shfl_xor(val, 1, 64);
          val = (d & 1) ? (part * sn + val * c) : (val * c - part * sn);
        }
        vals[r] = val;
      }
      const int mbase = m0 + wm + i * 16 + quad * 4;   // 4 consecutive s
      const int b = mbase >> 11, s0 = mbase & 2047;
      const int bh = (b << 4) + h;
      if (which == 0) {
#pragma unroll
        for (int r = 0; r < 4; ++r)
          qo[((size_t)bh * 2048 + s0 + r) * 64 + d] = f2b(vals[r]);
      } else if (which == 1) {
        // tiled: base = (bh*32 + s>>6)*4096 + ((d>>3)*64 + (s&63))*8 + (d&7)
#pragma unroll
        for (int r = 0; r < 4; ++r) {
          const int s = s0 + r;
          ko[((size_t)bh * 32 + (s >> 6)) * 4096 +
             (size_t)(((d >> 3) * 64 + (s & 63))) * 8 + (d & 7)] = f2b(vals[r]);
        }
      } else {
        // V^T tiled, 4 consecutive s -> one uint2 (8B) store
        uint32_t w0 = (uint32_t)f2b(vals[0]) | ((uint32_t)f2b(vals[1]) << 16);
        uint32_t w1 = (uint32_t)f2b(vals[2]) | ((uint32_t)f2b(vals[3]) << 16);
        uint2 pk; pk.x = w0; pk.y = w1;
        *(uint2*)(vo + ((size_t)bh * 32 + (s0 >> 6)) * 4096 +
                  (size_t)((((s0 & 63) >> 3) * 64 + d)) * 8 + (s0 & 7)) = pk;
      }
    }
  }
}

// ---------------- flash attention ----------------
// grid (bh=32, 16); block 512 thr = 8 waves; wave w owns q-rows w*16..w*16+15.
// S^T = K*Q^T formulation: t in-lane, m = lane&15.
// R7: K/V double-buffer with static ping/pong (nkv = 2*qb+2 is even).
__global__ __launch_bounds__(512, 4) void flash_kernel(
    const unsigned short* __restrict__ Q,    // [32][2048][64] row-major
    const unsigned short* __restrict__ K,    // tiled frag-major (see qkv)
    const unsigned short* __restrict__ VT,   // V^T tiled frag-major
    unsigned short* __restrict__ O)          // [2][2048][1024]
{
  constexpr int PSTRIDE = 72;                // Ps row stride (shorts)
  __shared__ unsigned short Ks[2][4096];     // 2 x 8 KB, chunk L = c*64 + t
  __shared__ unsigned short Vs[2][4096];     // 2 x 8 KB, chunk L = ct*64 + d
  __shared__ unsigned short Ps[128 * PSTRIDE];
  const int tid = threadIdx.x;
  const int w = tid >> 6, l = tid & 63, lm = l & 15, quad = l >> 4;
  const int bh = blockIdx.x, qb = 15 - blockIdx.y;   // heavy q-blocks first
  const int mrow_g = qb * 128 + w * 16 + lm;         // this lane's softmax row

  // Q fragment to registers: lane reads row (qb*128+w*16+lm), 8 d at quad*8
  const size_t qbase = ((size_t)bh * 2048 + (size_t)qb * 128) * 64;
  bf16x8 aq[2];
#pragma unroll
  for (int kc = 0; kc < 2; ++kc)
    aq[kc] = *(const bf16x8*)(Q + qbase + (size_t)(w * 16 + lm) * 64 + kc * 32 + quad * 8);

  const f32x4 fzero = {0.f, 0.f, 0.f, 0.f};
  f32x4 Oacc[4];
#pragma unroll
  for (int jo = 0; jo < 4; ++jo) Oacc[jo] = fzero;
  float m_i = -1e30f, l_i = 0.f;

  auto stageKV = [&](unsigned short* Kb, unsigned short* Vb, int kt) {
    const size_t tbase = ((size_t)bh * 32 + kt) * 4096;
    async16(K  + tbase + (size_t)tid * 8, Kb + (size_t)w * 512);
    async16(VT + tbase + (size_t)tid * 8, Vb + (size_t)w * 512);
  };

  // one K/V tile: QK^T -> online softmax -> O += P V
  auto kvtile = [&](const unsigned short* Ksb, const unsigned short* Vsb, int kt) {
    // S^T = K * Q^T : Sc[tb] holds t = tb*16+quad*4+r (rows), m = lm (col)
    f32x4 Sc[4];
#pragma unroll
    for (int tb = 0; tb < 4; ++tb) Sc[tb] = fzero;
#pragma unroll
    for (int kc = 0; kc < 2; ++kc) {
      bf16x8 ak[4];
#pragma unroll
      for (int tb = 0; tb < 4; ++tb)
        ak[tb] = *(const bf16x8*)(Ksb + (size_t)(((kc * 4 + quad) * 64 + tb * 16 + lm)) * 8);
#pragma unroll
      for (int tb = 0; tb < 4; ++tb)
        Sc[tb] = __builtin_amdgcn_mfma_f32_16x16x32_bf16(ak[tb], aq[kc], Sc[tb], 0, 0, 0);
    }

    // scale + causal mask.  Mask needed iff tile's max t (kt*64+63) exceeds
    // this wave's MIN row (qb*128 + w*16).
    const bool needmask = (kt * 64 + 63 > qb * 128 + w * 16);
    const int  mrel = mrow_g - kt * 64;      // mask t-index > mrel
    float mx = -1e30f;
#pragma unroll
    for (int tb = 0; tb < 4; ++tb) {
#pragma unroll
      for (int r = 0; r < 4; ++r) {
        float s = Sc[tb][r] * 0.125f;        // 1/sqrt(64)
        if (needmask && (tb * 16 + quad * 4 + r > mrel)) s = -1e30f;
        Sc[tb][r] = s;
        mx = fmaxf(mx, s);
      }
    }
    mx = fmaxf(mx, __shfl_xor(mx, 16, 64));
    mx = fmaxf(mx, __shfl_xor(mx, 32, 64));
    const float mnew  = fmaxf(m_i, mx);
    const float alpha = __expf(m_i - mnew);
    m_i = mnew;

    // exp, pack 4 consecutive t -> b64 write into Ps[m][t]
    float ps = 0.f;
#pragma unroll
    for (int tb = 0; tb < 4; ++tb) {
      float p0 = __expf(Sc[tb][0] - mnew), p1 = __expf(Sc[tb][1] - mnew);
      float p2 = __expf(Sc[tb][2] - mnew), p3 = __expf(Sc[tb][3] - mnew);
      ps += (p0 + p1) + (p2 + p3);
      uint2 pk;
      pk.x = (uint32_t)f2b(p0) | ((uint32_t)f2b(p1) << 16);
      pk.y = (uint32_t)f2b(p2) | ((uint32_t)f2b(p3) << 16);
      *(uint2*)(Ps + (size_t)(w * 16 + lm) * PSTRIDE + tb * 16 + quad * 4) = pk;
    }
    ps += __shfl_xor(ps, 16, 64);
    ps += __shfl_xor(ps, 32, 64);
    l_i = l_i * alpha + ps;

    // rescale Oacc: alpha lives per m=lm; O rows are quad*4+r -> shuffle
    float af4[4];
#pragma unroll
    for (int r = 0; r < 4; ++r) af4[r] = __shfl(alpha, quad * 4 + r, 64);
#pragma unroll
    for (int jo = 0; jo < 4; ++jo)
#pragma unroll
      for (int r = 0; r < 4; ++r) Oacc[jo][r] *= af4[r];

    // O += P V  (wave-private Ps rows; lgkmcnt orders write->read in-wave)
#pragma unroll
    for (int kc = 0; kc < 2; ++kc) {
      bf16x8 ap = *(const bf16x8*)(Ps + (size_t)(w * 16 + lm) * PSTRIDE + kc * 32 + quad * 8);
      bf16x8 bv[4];
#pragma unroll
      for (int jo = 0; jo < 4; ++jo)
        bv[jo] = *(const bf16x8*)(Vsb + (size_t)(((kc * 4 + quad) * 64 + jo * 16 + lm)) * 8);
#pragma unroll
      for (int jo = 0; jo < 4; ++jo)
        Oacc[jo] = __builtin_amdgcn_mfma_f32_16x16x32_bf16(ap, bv[jo], Oacc[jo], 0, 0, 0);
    }
  };

  const int nkv = 2 * qb + 2;                // even
  stageKV(Ks[0], Vs[0], 0);
  __syncthreads();                           // tile 0 resident
#pragma unroll 1
  for (int kt = 0; kt < nkv; kt += 2) {
    stageKV(Ks[1], Vs[1], kt + 1);           // next K/V in flight
    kvtile(Ks[0], Vs[0], kt);
    __syncthreads();                         // tile kt+1 resident; buf0 free
    if (kt + 2 < nkv) stageKV(Ks[0], Vs[0], kt + 2);
    kvtile(Ks[1], Vs[1], kt + 1);
    __syncthreads();                         // tile kt+2 resident; buf1 free
  }

  // epilogue: normalize, write o_bf (b, s, h*64+d)
  float lf[4];
#pragma unroll
  for (int r = 0; r < 4; ++r) lf[r] = 1.0f / __shfl(l_i, quad * 4 + r, 64);
  const int b = bh >> 4, h = bh & 15;
#pragma unroll
  for (int jo = 0; jo < 4; ++jo)
#pragma unroll
    for (int r = 0; r < 4; ++r) {
      const int s   = qb * 128 + w * 16 + quad * 4 + r;
      const int col = h * 64 + jo * 16 + lm;
      O[((size_t)b * 2048 + s) * 1024 + col] = f2b(Oacc[jo][r] * lf[r]);
    }
}

// ---------------- output projection GEMM ----------------
// out[4096,1024] = Obf[4096,1024] @ Wo[1024,1024]^T + bias (fp32 out).
// 64x128 tiles, BK=64, 512 blocks (2/CU), double-buffered, static ping/pong.
__global__ __launch_bounds__(256) void oproj_gemm_kernel(
    const unsigned short* __restrict__ A,    // o_bf [4096][1024]
    const unsigned short* __restrict__ W,    // wo_bf [1024][1024]
    const float* __restrict__ bias,
    float* __restrict__ out)
{
  __shared__ unsigned short As[2][64 * 64];   // 2 x 8 KB
  __shared__ unsigned short Bs[2][128 * 64];  // 2 x 16 KB
  const int tid = threadIdx.x;
  const int w = tid >> 6, l = tid & 63;
  const int lm = l & 15, quad = l >> 4;
  const int m0 = blockIdx.y * 64;
  const int n0 = blockIdx.x * 128;

  const f32x4 fzero = {0.f, 0.f, 0.f, 0.f};
  f32x4 acc[4][2];
#pragma unroll
  for (int i = 0; i < 4; ++i)
#pragma unroll
    for (int j = 0; j < 2; ++j) acc[i][j] = fzero;

  auto stage_tile = [&](unsigned short* Asb, unsigned short* Bsb, int k0) {
    // A: 64 rows x 8 kc = 512 chunks; 2 per thread
#pragma unroll
    for (int q = 0; q < 2; ++q) {
      const int row = w * 16 + lm;
      const int kc  = quad + 4 * q;
      async16(A + (size_t)(m0 + row) * 1024 + k0 + kc * 8,
              Asb + ((size_t)w * 128 + 64 * q) * 8);
    }
    // B: 128 rows x 8 kc = 1024 chunks; 4 per thread
#pragma unroll
    for (int q = 0; q < 4; ++q) {
      const int row = w * 16 + lm + (q & 1) * 64;
      const int kc  = quad + 4 * (q >> 1);
      async16(W + (size_t)(n0 + row) * 1024 + k0 + kc * 8,
              Bsb + ((size_t)(w + 4 * (q & 1)) * 128 + 64 * (q >> 1)) * 8);
    }
  };
  auto compute_tile = [&](const unsigned short* Asb, const unsigned short* Bsb) {
#pragma unroll
    for (int kk = 0; kk < 2; ++kk) {
      bf16x8 af[4], bfc[2];
#pragma unroll
      for (int i = 0; i < 4; ++i)
        af[i] = *(const bf16x8*)(Asb + (size_t)((i * 128 + kk * 64 + l)) * 8);
#pragma unroll
      for (int j = 0; j < 2; ++j)
        bfc[j] = *(const bf16x8*)(Bsb + (size_t)(((w * 2 + j) * 128 + kk * 64 + l)) * 8);
#pragma unroll
      for (int i = 0; i < 4; ++i)
#pragma unroll
        for (int j = 0; j < 2; ++j)
          acc[i][j] = __builtin_amdgcn_mfma_f32_16x16x32_bf16(af[i], bfc[j], acc[i][j], 0, 0, 0);
    }
  };

  stage_tile(As[0], Bs[0], 0);
  __syncthreads();
#pragma unroll 1
  for (int t = 0; t < 14; t += 2) {
    stage_tile(As[1], Bs[1], (t + 1) * 64);
    compute_tile(As[0], Bs[0]);
    __syncthreads();
    stage_tile(As[0], Bs[0], (t + 2) * 64);
    compute_tile(As[1], Bs[1]);
    __syncthreads();
  }
  stage_tile(As[1], Bs[1], 15 * 64);
  compute_tile(As[0], Bs[0]);
  __syncthreads();
  compute_tile(As[1], Bs[1]);

#pragma unroll
  for (int i = 0; i < 4; ++i) {
#pragma unroll
    for (int j = 0; j < 2; ++j) {
      const int n = n0 + w * 32 + j * 16 + lm;
      const float bval = bias[n];
#pragma unroll
      for (int r = 0; r < 4; ++r) {
        const int m = m0 + i * 16 + quad * 4 + r;
        out[(size_t)m * 1024 + n] = acc[i][j][r] + bval;
      }
    }
  }
}

// ---------------- host launch ----------------
extern "C" void kernel_launch(void* const* d_in, const int* in_sizes, int n_in,
                              void* d_out, int out_size, void* d_ws, size_t ws_size,
                              hipStream_t stream) {
  (void)in_sizes; (void)n_in; (void)out_size; (void)ws_size;
  const float* x  = (const float*)d_in[0];
  const float* cp = (const float*)d_in[1];
  const float* sp = (const float*)d_in[2];
  const float* wq = (const float*)d_in[3];
  const float* bq = (const float*)d_in[4];
  const float* wk = (const float*)d_in[5];
  const float* bk = (const float*)d_in[6];
  const float* wv = (const float*)d_in[7];
  const float* bv = (const float*)d_in[8];
  const float* wo = (const float*)d_in[9];
  const float* bo = (const float*)d_in[10];
  float* out = (float*)d_out;

  unsigned short* xbf  = (unsigned short*)d_ws;          // 4M shorts
  unsigned short* wqkv = xbf  + (size_t)4 * 1024 * 1024; // 3M
  unsigned short* wobf = wqkv + (size_t)3 * 1024 * 1024; // 1M
  unsigned short* qbf  = wobf + (size_t)1 * 1024 * 1024; // 4M (bh,s,d)
  unsigned short* kbf  = qbf  + (size_t)4 * 1024 * 1024; // 4M (tiled frag-major)
  unsigned short* vbf  = kbf  + (size_t)4 * 1024 * 1024; // 4M (V^T tiled)
  unsigned short* obf  = vbf  + (size_t)4 * 1024 * 1024; // 4M (b,s,h*64+d)

  hipLaunchKernelGGL(cast_kernel, dim3(4096), dim3(256), 0, stream, x, xbf, 1048576);
  hipLaunchKernelGGL(cast_w_kernel, dim3(4096), dim3(256), 0, stream,
                     wq, wk, wv, wo, wqkv, wobf);

  hipLaunchKernelGGL(qkv_gemm_kernel, dim3(24, 32), dim3(256), 0, stream,
                     xbf, wqkv, bq, bk, bv, cp, sp, qbf, kbf, vbf);
  hipLaunchKernelGGL(flash_kernel, dim3(32, 16), dim3(512), 0, stream,
                     qbf, kbf, vbf, obf);
  hipLaunchKernelGGL(oproj_gemm_kernel, dim3(8, 64), dim3(256), 0, stream,
                     obf, wobf, bo, out);
}